// Round 10
// baseline (14.167 us; speedup 1.0000x reference)
//
#include <hip/hip_runtime.h>
#include <math.h>

// 8-qubit statevector sim, FOUR elements per 64-lane wave (16 lanes each).
// Storage z (8 bits): z0-3 = lane sl (4 bits), z4-7 = reg K (k0..k3), 16 amps.
// Bit-level maps IDENTICAL to validated round-9:
//   Gates: q0:K3(fold U) q1:K2(fold T2) q2:K1(explicit) q3:K0(fold T1)
//          q4:xor8(sel sl3) q5:xor7(sl2) q6:xor2(sl1^sl2) q7:xor1(sl0^sl2)
//   Product comps: q0:b01^K3 q1:b01^K2^K3 q2:K1^K2 q3:K0^K1 q4:sl3^K0
//          q5:sl2^sl3 q6:sl1 q7:sl0^sl1        (b01 = sl0^sl2)
//   Phases: E0(±K3),E1(±K2) in U; E2(±K1),E3(±K0) in T1; lam = ±h4(sl3)
//          ±h5(sl2) ±h6(sl1^sl2) ±h7(sl0^sl2)
//   Z Walsh: k-masks q0:0x7 q1:0xC q2:0xE q3..7:0xF; lane picks
//          q0:0xF q1:0 q2:0 q3:0 q4:8 q5:0xC q6:0xA q7:0xF
// NEW this round (mechanics only, same math): k-dimension STREAMED in
// (k,k|2) pairs — amps[16]/P[16] never materialize; peak live regs ~55
// (was ~90+, spill suspect at the 128-VGPR launch_bounds(256,4) budget).

#define DEVINL __device__ __forceinline__

DEVINL void fast_sincos_half(float x, float& s, float& c) {
    const float r = x * 0.07957747154594767f;   // (x/2)/(2*pi): HW trig in revolutions
    s = __builtin_amdgcn_sinf(r);
    c = __builtin_amdgcn_cosf(r);
}

DEVINL float fast_tanh(float x) {
    const float t = __builtin_amdgcn_exp2f(x * 2.8853900817779268f);  // e^{2x}
    return 1.0f - 2.0f * __builtin_amdgcn_rcpf(t + 1.0f);
}

DEVINL void cmul(float ar, float ai, float br, float bi, float& cr, float& ci) {
    cr = ar*br - ai*bi;  ci = ar*bi + ai*br;
}
DEVINL void cmulc(float ar, float ai, float br, float bi, float& cr, float& ci) {
    cr = ar*br + ai*bi;  ci = ar*bi - ai*br;   // conj(a)*b
}

template<int CTRL>
DEVINL float dpp_perm(float x) {
    return __int_as_float(__builtin_amdgcn_update_dpp(
        __float_as_int(x), __float_as_int(x), CTRL, 0xF, 0xF, false));
}
// DPP: xor1=0xB1 (quad 1,0,3,2); xor2=0x4E (2,3,0,1); xor3=0x1B (3,2,1,0);
//      xor7=0x141 (row_half_mirror); xor8=0x128 (row_ror:8).
template<int OFF>
DEVINL float swz(float x) {
    return __int_as_float(__builtin_amdgcn_ds_swizzle(__float_as_int(x), OFF));
}
// BitMode: src = ((l&and)|or)^xor. bcast lane15-of-16grp: 0x1F0;
// bcast lane0-of-16grp: 0x010.

// v = Rot(phi,theta,omega) * RX(x) * |0>   (layer-1, validated rounds 3-9)
DEVINL void qubit_vec(float x, float phi, float theta, float omega,
                      float& v0r, float& v0i, float& v1r, float& v1i)
{
    float s, c;   fast_sincos_half(x, s, c);
    float st, ct; fast_sincos_half(theta, st, ct);
    float sa, ca; fast_sincos_half(phi + omega, sa, ca);
    float sb, cb; fast_sincos_half(phi - omega, sb, cb);
    const float A = c*ct, B = s*st, C = c*st, D = s*ct;
    v0r = ca*A - sb*B;  v0i = cb*B - sa*A;
    v1r = cb*C + sa*D;  v1i = -(sb*C + ca*D);
}

__global__ __launch_bounds__(256, 4)
void qcirc_kernel(const float* __restrict__ inputs,
                  const float* __restrict__ hidden,
                  float* __restrict__ out, int B)
{
    __shared__ __align__(16) float lds[1024];   // 16 elem x 8 qubits x 8 floats

    const int t  = threadIdx.x;
    const int e  = blockIdx.x * 16 + (t >> 4);
    if (e >= B) return;
    const int sl = t & 15;
    const int q  = sl & 7;                 // owned qubit (2x redundant owners)
    const int eb = (t >> 4) * 64;          // element base in LDS (floats)
    const int sl0 = sl & 1, sl1 = (sl >> 1) & 1, sl2 = (sl >> 2) & 1,
              sl3 = (sl >> 3) & 1;

    // ---- hoisted global loads (6 scalars) ----
    const float  x  = inputs[(size_t)e * 8 + q];
    const float* hb = hidden + (size_t)e * 48 + q * 3;
    const float ph1 = hb[0], th1 = hb[1], om1 = hb[2];
    const float ph2 = hb[24], th2 = hb[25];        // layer-2 omega cancels

    // ---- owner compute; lanes sl<8 write the per-element LDS table ----
    float ov0r, ov0i, ov1r, ov1i;
    qubit_vec(x, ph1, th1, om1, ov0r, ov0i, ov1r, ov1i);
    float s2o, c2o; fast_sincos_half(th2, s2o, c2o);
    const float ho = ph2 * 0.07957747154594767f;   // phi2/2 in revolutions
    const float Ec = __builtin_amdgcn_cosf(ho);
    const float Es = __builtin_amdgcn_sinf(ho);
    const float Av = (q < 4) ? Ec : ho;            // q<4: E=(cos,sin); else raw h
    const float Bv = (q < 4) ? Es : 0.f;

    if (sl < 8) {
        *(float4*)(lds + eb + q*8)     = make_float4(ov0r, ov0i, ov1r, ov1i);
        *(float4*)(lds + eb + q*8 + 4) = make_float4(c2o, s2o, Av, Bv);
    }
    // producer and consumers are the SAME wave: lgkmcnt ordering suffices.

    // ---- lane product L over q5,q6,q7 ----
    float Lr, Li;
    {
        const float4 r5 = *(const float4*)(lds + eb + 40);
        const float4 r6 = *(const float4*)(lds + eb + 48);
        const float4 r7 = *(const float4*)(lds + eb + 56);
        const int s5 = sl2 ^ sl3, s6 = sl1, s7 = sl0 ^ sl1;
        const float a5r = s5 ? r5.z : r5.x, a5i = s5 ? r5.w : r5.y;
        const float a6r = s6 ? r6.z : r6.x, a6i = s6 ? r6.w : r6.y;
        const float a7r = s7 ? r7.z : r7.x, a7i = s7 ? r7.w : r7.y;
        float tr, ti;
        cmul(a5r, a5i, a6r, a6i, tr, ti);
        cmul(tr, ti, a7r, a7i, Lr, Li);
    }
    // ---- lam phase on L (raw h of q4..q7) ----
    {
        const float h4 = lds[eb + 4*8 + 6];
        const float h5 = lds[eb + 5*8 + 6];
        const float h6 = lds[eb + 6*8 + 6];
        const float h7 = lds[eb + 7*8 + 6];
        const float lam = (sl3 ? h4 : -h4) + (sl2 ? h5 : -h5)
                        + ((sl1 ^ sl2) ? h6 : -h6) + ((sl0 ^ sl2) ? h7 : -h7);
        const float Pc = __builtin_amdgcn_cosf(lam);
        const float Ps = __builtin_amdgcn_sinf(lam);
        float tr, ti; cmul(Lr, Li, Pc, Ps, tr, ti); Lr = tr; Li = ti;
    }

    // ---- U[(K3,K2)] = w0[K3]*w1[K2^K3]*E0^{±K3}E1^{±K2}, q0 folded ----
    float Ur[4], Ui[4];
    {
        const float4 r0 = *(const float4*)(lds + eb + 0);
        const float4 r1 = *(const float4*)(lds + eb + 8);
        const float2 E0 = *(const float2*)(lds + eb + 0*8 + 6);
        const float2 E1 = *(const float2*)(lds + eb + 1*8 + 6);
        const int b01 = sl0 ^ sl2;
        const float w00r = b01 ? r0.z : r0.x, w00i = b01 ? r0.w : r0.y;
        const float w01r = b01 ? r0.x : r0.z, w01i = b01 ? r0.y : r0.w;
        const float w10r = b01 ? r1.z : r1.x, w10i = b01 ? r1.w : r1.y;
        const float w11r = b01 ? r1.x : r1.z, w11i = b01 ? r1.y : r1.w;
        const float aa = E0.x*E1.x, bb = E0.y*E1.y, cc = E0.x*E1.y, dd = E0.y*E1.x;
        const float P3r = aa - bb, P3i = cc + dd;   // E0*E1
        const float P1r = aa + bb, P1i = cc - dd;   // conj(E0)*E1
        float tr, ti;
        cmul(w00r,w00i, w10r,w10i, tr,ti); cmulc(P3r,P3i, tr,ti, Ur[0],Ui[0]);
        cmul(w00r,w00i, w11r,w11i, tr,ti); cmul (P1r,P1i, tr,ti, Ur[1],Ui[1]);
        cmul(w01r,w01i, w11r,w11i, tr,ti); cmulc(P1r,P1i, tr,ti, Ur[2],Ui[2]);
        cmul(w01r,w01i, w10r,w10i, tr,ti); cmul (P3r,P3i, tr,ti, Ur[3],Ui[3]);
        const float2 cs0 = *(const float2*)(lds + eb + 0*8 + 4);   // q0 fold (K3)
        #pragma unroll
        for (int j = 0; j < 2; ++j) {
            const float lr = Ur[j], li = Ui[j], hr = Ur[j+2], hi = Ui[j+2];
            Ur[j]   = cs0.x*lr - cs0.y*hr;  Ui[j]   = cs0.x*li - cs0.y*hi;
            Ur[j+2] = cs0.y*lr + cs0.x*hr;  Ui[j+2] = cs0.y*li + cs0.x*hi;
        }
    }

    // ---- T2[(K3,K2,K1)] = U[m>>1] * v2[K1^K2], q1 folded (K2) ----
    float T2r[8], T2i[8];
    {
        const float4 r2 = *(const float4*)(lds + eb + 16);
        #pragma unroll
        for (int m = 0; m < 8; ++m) {
            const int idx = (m & 1) ^ ((m >> 1) & 1);
            const float vr = idx ? r2.z : r2.x;
            const float vi = idx ? r2.w : r2.y;
            cmul(Ur[m >> 1], Ui[m >> 1], vr, vi, T2r[m], T2i[m]);
        }
        const float2 cs1 = *(const float2*)(lds + eb + 1*8 + 4);
        #pragma unroll
        for (int m = 0; m < 8; ++m) {
            if (m & 2) continue;
            const int m1 = m | 2;
            const float lr = T2r[m], li = T2i[m], hr = T2r[m1], hi = T2i[m1];
            T2r[m]  = cs1.x*lr - cs1.y*hr;  T2i[m]  = cs1.x*li - cs1.y*hi;
            T2r[m1] = cs1.y*lr + cs1.x*hr;  T2i[m1] = cs1.y*li + cs1.x*hi;
        }
    }

    // ---- T1[(K1,K0)] = v3[K0^K1]E2^{±K1} * (v4sw[K0]E3^{±K0}*L), q3 folded ----
    float T1r[4], T1i[4];
    {
        const float4 r3 = *(const float4*)(lds + eb + 24);
        const float4 r4 = *(const float4*)(lds + eb + 32);
        const float2 E2 = *(const float2*)(lds + eb + 2*8 + 6);
        const float2 E3 = *(const float2*)(lds + eb + 3*8 + 6);
        const float w40r = sl3 ? r4.z : r4.x, w40i = sl3 ? r4.w : r4.y;
        const float w41r = sl3 ? r4.x : r4.z, w41i = sl3 ? r4.y : r4.w;
        float D0r, D0i, D1r, D1i;
        cmulc(E3.x, E3.y, w40r, w40i, D0r, D0i);     // w4[0]*conj(E3)
        cmul (w41r, w41i, E3.x, E3.y, D1r, D1i);     // w4[1]*E3
        float LD0r, LD0i, LD1r, LD1i;
        cmul(D0r, D0i, Lr, Li, LD0r, LD0i);
        cmul(D1r, D1i, Lr, Li, LD1r, LD1i);
        float e00r,e00i, e01r,e01i, e10r,e10i, e11r,e11i;
        cmulc(E2.x, E2.y, r3.x, r3.y, e00r, e00i);   // v3[0]*conj(E2)
        cmulc(E2.x, E2.y, r3.z, r3.w, e01r, e01i);   // v3[1]*conj(E2)
        cmul (r3.z, r3.w, E2.x, E2.y, e10r, e10i);   // v3[1]*E2
        cmul (r3.x, r3.y, E2.x, E2.y, e11r, e11i);   // v3[0]*E2
        cmul(e00r, e00i, LD0r, LD0i, T1r[0], T1i[0]);
        cmul(e01r, e01i, LD1r, LD1i, T1r[1], T1i[1]);
        cmul(e10r, e10i, LD0r, LD0i, T1r[2], T1i[2]);
        cmul(e11r, e11i, LD1r, LD1i, T1r[3], T1i[3]);
        const float2 cs3 = *(const float2*)(lds + eb + 3*8 + 4);   // q3 fold (K0)
        #pragma unroll
        for (int j = 0; j < 4; j += 2) {
            const float lr = T1r[j], li = T1i[j], hr = T1r[j+1], hi = T1i[j+1];
            T1r[j]   = cs3.x*lr - cs3.y*hr;  T1i[j]   = cs3.x*li - cs3.y*hi;
            T1r[j+1] = cs3.y*lr + cs3.x*hr;  T1i[j+1] = cs3.y*li + cs3.x*hi;
        }
    }

    // ---- streamed k: init pair -> q2 gate -> lane gates -> P -> Walsh acc ----
    const float2 cs2 = *(const float2*)(lds + eb + 2*8 + 4);   // q2 (K1)
    const float2 cs4 = *(const float2*)(lds + eb + 4*8 + 4);
    const float2 cs5 = *(const float2*)(lds + eb + 5*8 + 4);
    const float2 cs6 = *(const float2*)(lds + eb + 6*8 + 4);
    const float2 cs7 = *(const float2*)(lds + eb + 7*8 + 4);
    const float se4 = sl3 ? cs4.y : -cs4.y;
    const float se5 = sl2 ? cs5.y : -cs5.y;
    const float se6 = (sl1 ^ sl2) ? cs6.y : -cs6.y;
    const float se7 = (sl0 ^ sl2) ? cs7.y : -cs7.y;

    float V7k = 0.f, VCk = 0.f, VEk = 0.f, VFk = 0.f;

    #pragma unroll
    for (int p = 0; p < 8; ++p) {
        const int kA = ((p & 6) << 1) | (p & 1);   // {0,1,4,5,8,9,12,13}
        const int kB = kA | 2;
        // init two amps from trees
        float aAr, aAi, aBr, aBi;
        cmul(T2r[kA >> 1], T2i[kA >> 1], T1r[kA & 3], T1i[kA & 3], aAr, aAi);
        cmul(T2r[kB >> 1], T2i[kB >> 1], T1r[kB & 3], T1i[kB & 3], aBr, aBi);
        // q2 gate (K1 pair): lo=kA, hi=kB
        float xr = cs2.x*aAr - cs2.y*aBr,  xi = cs2.x*aAi - cs2.y*aBi;
        float yr = cs2.y*aAr + cs2.x*aBr,  yi = cs2.y*aAi + cs2.x*aBi;
        // lane gates q4..q7 (DPP) on both amps
        xr = cs4.x*xr + se4*dpp_perm<0x128>(xr);  xi = cs4.x*xi + se4*dpp_perm<0x128>(xi);
        yr = cs4.x*yr + se4*dpp_perm<0x128>(yr);  yi = cs4.x*yi + se4*dpp_perm<0x128>(yi);
        xr = cs5.x*xr + se5*dpp_perm<0x141>(xr);  xi = cs5.x*xi + se5*dpp_perm<0x141>(xi);
        yr = cs5.x*yr + se5*dpp_perm<0x141>(yr);  yi = cs5.x*yi + se5*dpp_perm<0x141>(yi);
        xr = cs6.x*xr + se6*dpp_perm<0x4E>(xr);   xi = cs6.x*xi + se6*dpp_perm<0x4E>(xi);
        yr = cs6.x*yr + se6*dpp_perm<0x4E>(yr);   yi = cs6.x*yi + se6*dpp_perm<0x4E>(yi);
        xr = cs7.x*xr + se7*dpp_perm<0xB1>(xr);   xi = cs7.x*xi + se7*dpp_perm<0xB1>(xi);
        yr = cs7.x*yr + se7*dpp_perm<0xB1>(yr);   yi = cs7.x*yi + se7*dpp_perm<0xB1>(yi);
        // probabilities
        const float PA = xr*xr + xi*xi;
        const float PB = yr*yr + yi*yi;
        // accumulate k-Walsh with compile-time signs
        V7k += (__builtin_popcount(kA & 0x7) & 1) ? -PA : PA;
        V7k += (__builtin_popcount(kB & 0x7) & 1) ? -PB : PB;
        VCk += (__builtin_popcount(kA & 0xC) & 1) ? -PA : PA;
        VCk += (__builtin_popcount(kB & 0xC) & 1) ? -PB : PB;
        VEk += (__builtin_popcount(kA & 0xE) & 1) ? -PA : PA;
        VEk += (__builtin_popcount(kB & 0xE) & 1) ? -PB : PB;
        VFk += (__builtin_popcount(kA & 0xF) & 1) ? -PA : PA;
        VFk += (__builtin_popcount(kB & 0xF) & 1) ? -PB : PB;
    }

    // ---- FWHT over 4 lane bits (ALL DPP; xor4 = xor7 o xor3) ----
    {
        const float g1 = (sl & 1) ? -1.f : 1.f;
        V7k = fmaf(g1, V7k, dpp_perm<0xB1>(V7k));
        VCk = fmaf(g1, VCk, dpp_perm<0xB1>(VCk));
        VEk = fmaf(g1, VEk, dpp_perm<0xB1>(VEk));
        VFk = fmaf(g1, VFk, dpp_perm<0xB1>(VFk));
        const float g2 = (sl & 2) ? -1.f : 1.f;
        V7k = fmaf(g2, V7k, dpp_perm<0x4E>(V7k));
        VCk = fmaf(g2, VCk, dpp_perm<0x4E>(VCk));
        VEk = fmaf(g2, VEk, dpp_perm<0x4E>(VEk));
        VFk = fmaf(g2, VFk, dpp_perm<0x4E>(VFk));
        const float g4 = (sl & 4) ? -1.f : 1.f;
        V7k = fmaf(g4, V7k, dpp_perm<0x1B>(dpp_perm<0x141>(V7k)));
        VCk = fmaf(g4, VCk, dpp_perm<0x1B>(dpp_perm<0x141>(VCk)));
        VEk = fmaf(g4, VEk, dpp_perm<0x1B>(dpp_perm<0x141>(VEk)));
        VFk = fmaf(g4, VFk, dpp_perm<0x1B>(dpp_perm<0x141>(VFk)));
        const float g8 = (sl & 8) ? -1.f : 1.f;
        V7k = fmaf(g8, V7k, dpp_perm<0x128>(V7k));
        VCk = fmaf(g8, VCk, dpp_perm<0x128>(VCk));
        VEk = fmaf(g8, VEk, dpp_perm<0x128>(VEk));
        VFk = fmaf(g8, VFk, dpp_perm<0x128>(VFk));
    }

    // ---- gather: q0:V7k@0xF q1:VCk@0 q2:VEk@0 q3:VFk@0 q4:VFk@8
    //              q5:VFk@0xC q6:VFk@0xA q7:VFk@0xF ----
    const float B7 = swz<0x1F0>(V7k);                // bcast lane15 of 16-grp
    const float BC = swz<0x010>(VCk);                // bcast lane0 of 16-grp
    const float BE = swz<0x010>(VEk);
    const int idx = (int)((0xFAC80000u >> ((sl & 7) * 4)) & 0xFu);
    const float BF = __shfl(VFk, (t & 0x30) | idx, 64);
    const float rsel = (sl == 0) ? B7 : (sl == 1) ? BC : (sl == 2) ? BE : BF;
    const float h = fast_tanh(rsel);
    if (sl < 8) {
        const size_t obase = (size_t)e * 8;
        out[obase + sl] = h;
        out[(size_t)B * 8 + obase + sl] = h;
    }
}

extern "C" void kernel_launch(void* const* d_in, const int* in_sizes, int n_in,
                              void* d_out, int out_size, void* d_ws, size_t ws_size,
                              hipStream_t stream)
{
    const float* inputs = (const float*)d_in[0];   // (B, 8) fp32
    const float* hidden = (const float*)d_in[1];   // (B, 2, 1, 8, 3) fp32
    float* out = (float*)d_out;                    // (2, B, 8) fp32 (tuple (h,h))
    const int B = in_sizes[0] / 8;                 // 16384
    const int blocks = (B + 15) / 16;              // 16 lanes per element
    hipLaunchKernelGGL(qcirc_kernel, dim3(blocks), dim3(256), 0, stream,
                       inputs, hidden, out, B);
}

// Round 11
// 12.513 us; speedup vs baseline: 1.1322x; 1.1322x over previous
//
#include <hip/hip_runtime.h>
#include <math.h>

// 8-qubit statevector sim, FOUR elements per 64-lane wave (16 lanes each).
// Storage z (8 bits): z0-3 = lane sl (4 bits), z4-7 = reg K (k0..k3), 16 amps.
// REVERT to the round-9 measured optimum (12.7 us). Bracketing experiments:
//   R7 (32-lane, 8 waves/SIMD): 13.5 | R8 (float2 pack): 14.8 |
//   R10 (k-streamed, ILP-narrow): 14.2  -> R9 batch form is the optimum:
//   16-wide independent amp updates feed the scheduler enough ILP to cover
//   DPP/VALU dependent latency at 4 waves/SIMD.
// Validated maps (rounds 2-9):
//   Gates: q0:K3(fold U) q1:K2(fold T2) q2:K1(explicit) q3:K0(fold T1)
//          q4:xor8(sel sl3) q5:xor7(sl2) q6:xor2(sl1^sl2) q7:xor1(sl0^sl2)
//   Product comps: q0:b01^K3 q1:b01^K2^K3 q2:K1^K2 q3:K0^K1 q4:sl3^K0
//          q5:sl2^sl3 q6:sl1 q7:sl0^sl1        (b01 = sl0^sl2)
//   Phases: E0(±K3),E1(±K2) in U; E2(±K1),E3(±K0) in T1; lam = ±h4(sl3)
//          ±h5(sl2) ±h6(sl1^sl2) ±h7(sl0^sl2)
//   Z Walsh: k-masks q0:0x7 q1:0xC q2:0xE q3..7:0xF; lane picks
//          q0:0xF q1:0 q2:0 q3:0 q4:8 q5:0xC q6:0xA q7:0xF

#define DEVINL __device__ __forceinline__

DEVINL void fast_sincos_half(float x, float& s, float& c) {
    const float r = x * 0.07957747154594767f;   // (x/2)/(2*pi): HW trig in revolutions
    s = __builtin_amdgcn_sinf(r);
    c = __builtin_amdgcn_cosf(r);
}

DEVINL float fast_tanh(float x) {
    const float t = __builtin_amdgcn_exp2f(x * 2.8853900817779268f);  // e^{2x}
    return 1.0f - 2.0f * __builtin_amdgcn_rcpf(t + 1.0f);
}

DEVINL void cmul(float ar, float ai, float br, float bi, float& cr, float& ci) {
    cr = ar*br - ai*bi;  ci = ar*bi + ai*br;
}
DEVINL void cmulc(float ar, float ai, float br, float bi, float& cr, float& ci) {
    cr = ar*br + ai*bi;  ci = ar*bi - ai*br;   // conj(a)*b
}

template<int CTRL>
DEVINL float dpp_perm(float x) {
    return __int_as_float(__builtin_amdgcn_update_dpp(
        __float_as_int(x), __float_as_int(x), CTRL, 0xF, 0xF, false));
}
// DPP: xor1=0xB1 (quad 1,0,3,2); xor2=0x4E (2,3,0,1); xor3=0x1B (3,2,1,0);
//      xor7=0x141 (row_half_mirror); xor8=0x128 (row_ror:8).
template<int OFF>
DEVINL float swz(float x) {
    return __int_as_float(__builtin_amdgcn_ds_swizzle(__float_as_int(x), OFF));
}
// BitMode: src = ((l&and)|or)^xor. bcast lane15-of-16grp: 0x1F0;
// bcast lane0-of-16grp: 0x010.

// v = Rot(phi,theta,omega) * RX(x) * |0>   (layer-1, validated rounds 3-9)
DEVINL void qubit_vec(float x, float phi, float theta, float omega,
                      float& v0r, float& v0i, float& v1r, float& v1i)
{
    float s, c;   fast_sincos_half(x, s, c);
    float st, ct; fast_sincos_half(theta, st, ct);
    float sa, ca; fast_sincos_half(phi + omega, sa, ca);
    float sb, cb; fast_sincos_half(phi - omega, sb, cb);
    const float A = c*ct, B = s*st, C = c*st, D = s*ct;
    v0r = ca*A - sb*B;  v0i = cb*B - sa*A;
    v1r = cb*C + sa*D;  v1i = -(sb*C + ca*D);
}

__global__ __launch_bounds__(256, 4)
void qcirc_kernel(const float* __restrict__ inputs,
                  const float* __restrict__ hidden,
                  float* __restrict__ out, int B)
{
    __shared__ __align__(16) float lds[1024];   // 16 elem x 8 qubits x 8 floats

    const int t  = threadIdx.x;
    const int e  = blockIdx.x * 16 + (t >> 4);
    if (e >= B) return;
    const int sl = t & 15;
    const int q  = sl & 7;                 // owned qubit (2x redundant owners)
    const int eb = (t >> 4) * 64;          // element base in LDS (floats)
    const int sl0 = sl & 1, sl1 = (sl >> 1) & 1, sl2 = (sl >> 2) & 1,
              sl3 = (sl >> 3) & 1;

    // ---- owner compute; lanes sl<8 write the per-element LDS table ----
    const float  x  = inputs[(size_t)e * 8 + q];
    const float* hb = hidden + (size_t)e * 48 + q * 3;
    const float ph1 = hb[0], th1 = hb[1], om1 = hb[2];
    const float ph2 = hb[24], th2 = hb[25];        // layer-2 omega cancels

    float ov0r, ov0i, ov1r, ov1i;
    qubit_vec(x, ph1, th1, om1, ov0r, ov0i, ov1r, ov1i);
    float s2o, c2o; fast_sincos_half(th2, s2o, c2o);
    const float ho = ph2 * 0.07957747154594767f;   // phi2/2 in revolutions
    const float Ec = __builtin_amdgcn_cosf(ho);
    const float Es = __builtin_amdgcn_sinf(ho);
    const float Av = (q < 4) ? Ec : ho;            // q<4: E=(cos,sin); else raw h
    const float Bv = (q < 4) ? Es : 0.f;

    if (sl < 8) {
        *(float4*)(lds + eb + q*8)     = make_float4(ov0r, ov0i, ov1r, ov1i);
        *(float4*)(lds + eb + q*8 + 4) = make_float4(c2o, s2o, Av, Bv);
    }
    // producer and consumers are the SAME wave: lgkmcnt ordering suffices.

    // ---- lane product L over q5,q6,q7 ----
    float Lr, Li;
    {
        const float4 r5 = *(const float4*)(lds + eb + 40);
        const float4 r6 = *(const float4*)(lds + eb + 48);
        const float4 r7 = *(const float4*)(lds + eb + 56);
        const int s5 = sl2 ^ sl3, s6 = sl1, s7 = sl0 ^ sl1;
        const float a5r = s5 ? r5.z : r5.x, a5i = s5 ? r5.w : r5.y;
        const float a6r = s6 ? r6.z : r6.x, a6i = s6 ? r6.w : r6.y;
        const float a7r = s7 ? r7.z : r7.x, a7i = s7 ? r7.w : r7.y;
        float tr, ti;
        cmul(a5r, a5i, a6r, a6i, tr, ti);
        cmul(tr, ti, a7r, a7i, Lr, Li);
    }
    // ---- lam phase on L (raw h of q4..q7) ----
    {
        const float h4 = lds[eb + 4*8 + 6];
        const float h5 = lds[eb + 5*8 + 6];
        const float h6 = lds[eb + 6*8 + 6];
        const float h7 = lds[eb + 7*8 + 6];
        const float lam = (sl3 ? h4 : -h4) + (sl2 ? h5 : -h5)
                        + ((sl1 ^ sl2) ? h6 : -h6) + ((sl0 ^ sl2) ? h7 : -h7);
        const float Pc = __builtin_amdgcn_cosf(lam);
        const float Ps = __builtin_amdgcn_sinf(lam);
        float tr, ti; cmul(Lr, Li, Pc, Ps, tr, ti); Lr = tr; Li = ti;
    }

    // ---- U[(K3,K2)] = w0[K3]*w1[K2^K3]*E0^{±K3}E1^{±K2}, q0 folded ----
    float Ur[4], Ui[4];
    {
        const float4 r0 = *(const float4*)(lds + eb + 0);
        const float4 r1 = *(const float4*)(lds + eb + 8);
        const float2 E0 = *(const float2*)(lds + eb + 0*8 + 6);
        const float2 E1 = *(const float2*)(lds + eb + 1*8 + 6);
        const int b01 = sl0 ^ sl2;
        const float w00r = b01 ? r0.z : r0.x, w00i = b01 ? r0.w : r0.y;
        const float w01r = b01 ? r0.x : r0.z, w01i = b01 ? r0.y : r0.w;
        const float w10r = b01 ? r1.z : r1.x, w10i = b01 ? r1.w : r1.y;
        const float w11r = b01 ? r1.x : r1.z, w11i = b01 ? r1.y : r1.w;
        const float aa = E0.x*E1.x, bb = E0.y*E1.y, cc = E0.x*E1.y, dd = E0.y*E1.x;
        const float P3r = aa - bb, P3i = cc + dd;   // E0*E1
        const float P1r = aa + bb, P1i = cc - dd;   // conj(E0)*E1
        float tr, ti;
        cmul(w00r,w00i, w10r,w10i, tr,ti); cmulc(P3r,P3i, tr,ti, Ur[0],Ui[0]);
        cmul(w00r,w00i, w11r,w11i, tr,ti); cmul (P1r,P1i, tr,ti, Ur[1],Ui[1]);
        cmul(w01r,w01i, w11r,w11i, tr,ti); cmulc(P1r,P1i, tr,ti, Ur[2],Ui[2]);
        cmul(w01r,w01i, w10r,w10i, tr,ti); cmul (P3r,P3i, tr,ti, Ur[3],Ui[3]);
        const float2 cs0 = *(const float2*)(lds + eb + 0*8 + 4);   // q0 fold (K3)
        #pragma unroll
        for (int j = 0; j < 2; ++j) {
            const float lr = Ur[j], li = Ui[j], hr = Ur[j+2], hi = Ui[j+2];
            Ur[j]   = cs0.x*lr - cs0.y*hr;  Ui[j]   = cs0.x*li - cs0.y*hi;
            Ur[j+2] = cs0.y*lr + cs0.x*hr;  Ui[j+2] = cs0.y*li + cs0.x*hi;
        }
    }

    // ---- T2[(K3,K2,K1)] = U[m>>1] * v2[K1^K2], q1 folded (K2) ----
    float T2r[8], T2i[8];
    {
        const float4 r2 = *(const float4*)(lds + eb + 16);
        #pragma unroll
        for (int m = 0; m < 8; ++m) {
            const int idx = (m & 1) ^ ((m >> 1) & 1);
            const float vr = idx ? r2.z : r2.x;
            const float vi = idx ? r2.w : r2.y;
            cmul(Ur[m >> 1], Ui[m >> 1], vr, vi, T2r[m], T2i[m]);
        }
        const float2 cs1 = *(const float2*)(lds + eb + 1*8 + 4);
        #pragma unroll
        for (int m = 0; m < 8; ++m) {
            if (m & 2) continue;
            const int m1 = m | 2;
            const float lr = T2r[m], li = T2i[m], hr = T2r[m1], hi = T2i[m1];
            T2r[m]  = cs1.x*lr - cs1.y*hr;  T2i[m]  = cs1.x*li - cs1.y*hi;
            T2r[m1] = cs1.y*lr + cs1.x*hr;  T2i[m1] = cs1.y*li + cs1.x*hi;
        }
    }

    // ---- T1[(K1,K0)] = v3[K0^K1]E2^{±K1} * (v4sw[K0]E3^{±K0}*L), q3 folded ----
    float T1r[4], T1i[4];
    {
        const float4 r3 = *(const float4*)(lds + eb + 24);
        const float4 r4 = *(const float4*)(lds + eb + 32);
        const float2 E2 = *(const float2*)(lds + eb + 2*8 + 6);
        const float2 E3 = *(const float2*)(lds + eb + 3*8 + 6);
        const float w40r = sl3 ? r4.z : r4.x, w40i = sl3 ? r4.w : r4.y;
        const float w41r = sl3 ? r4.x : r4.z, w41i = sl3 ? r4.y : r4.w;
        float D0r, D0i, D1r, D1i;
        cmulc(E3.x, E3.y, w40r, w40i, D0r, D0i);     // w4[0]*conj(E3)
        cmul (w41r, w41i, E3.x, E3.y, D1r, D1i);     // w4[1]*E3
        float LD0r, LD0i, LD1r, LD1i;
        cmul(D0r, D0i, Lr, Li, LD0r, LD0i);
        cmul(D1r, D1i, Lr, Li, LD1r, LD1i);
        float e00r,e00i, e01r,e01i, e10r,e10i, e11r,e11i;
        cmulc(E2.x, E2.y, r3.x, r3.y, e00r, e00i);   // v3[0]*conj(E2)
        cmulc(E2.x, E2.y, r3.z, r3.w, e01r, e01i);   // v3[1]*conj(E2)
        cmul (r3.z, r3.w, E2.x, E2.y, e10r, e10i);   // v3[1]*E2
        cmul (r3.x, r3.y, E2.x, E2.y, e11r, e11i);   // v3[0]*E2
        cmul(e00r, e00i, LD0r, LD0i, T1r[0], T1i[0]);
        cmul(e01r, e01i, LD1r, LD1i, T1r[1], T1i[1]);
        cmul(e10r, e10i, LD0r, LD0i, T1r[2], T1i[2]);
        cmul(e11r, e11i, LD1r, LD1i, T1r[3], T1i[3]);
        const float2 cs3 = *(const float2*)(lds + eb + 3*8 + 4);   // q3 fold (K0)
        #pragma unroll
        for (int j = 0; j < 4; j += 2) {
            const float lr = T1r[j], li = T1i[j], hr = T1r[j+1], hi = T1i[j+1];
            T1r[j]   = cs3.x*lr - cs3.y*hr;  T1i[j]   = cs3.x*li - cs3.y*hi;
            T1r[j+1] = cs3.y*lr + cs3.x*hr;  T1i[j+1] = cs3.y*li + cs3.x*hi;
        }
    }

    // ---- init 16 amps: amp[k] = T2[k>>1] * T1[k&3] ----
    float ar[16], ai[16];
    #pragma unroll
    for (int k = 0; k < 16; ++k)
        cmul(T2r[k >> 1], T2i[k >> 1], T1r[k & 3], T1i[k & 3], ar[k], ai[k]);

    // ---- q2 gate (mask K1 = reg bit1, straddles trees) ----
    {
        const float2 cs = *(const float2*)(lds + eb + 2*8 + 4);
        #pragma unroll
        for (int k = 0; k < 16; ++k) {
            if (k & 2) continue;
            const int k1 = k | 2;
            const float lr = ar[k], li = ai[k], hr = ar[k1], hi = ai[k1];
            ar[k]  = cs.x*lr - cs.y*hr;  ai[k]  = cs.x*li - cs.y*hi;
            ar[k1] = cs.y*lr + cs.x*hr;  ai[k1] = cs.y*li + cs.x*hi;
        }
    }

    // ---- lane gates q4..q7 (ALL DPP, VALU pipe; 16-wide ILP) ----
    {   // q4: xor8 (row_ror:8), sel sl3
        const float2 cs = *(const float2*)(lds + eb + 4*8 + 4);
        const float se = sl3 ? cs.y : -cs.y;
        #pragma unroll
        for (int k = 0; k < 16; ++k) {
            ar[k] = cs.x*ar[k] + se*dpp_perm<0x128>(ar[k]);
            ai[k] = cs.x*ai[k] + se*dpp_perm<0x128>(ai[k]);
        }
    }
    {   // q5: xor7 (row_half_mirror), sel sl2
        const float2 cs = *(const float2*)(lds + eb + 5*8 + 4);
        const float se = sl2 ? cs.y : -cs.y;
        #pragma unroll
        for (int k = 0; k < 16; ++k) {
            ar[k] = cs.x*ar[k] + se*dpp_perm<0x141>(ar[k]);
            ai[k] = cs.x*ai[k] + se*dpp_perm<0x141>(ai[k]);
        }
    }
    {   // q6: xor2 (quad), sel sl1^sl2
        const float2 cs = *(const float2*)(lds + eb + 6*8 + 4);
        const float se = (sl1 ^ sl2) ? cs.y : -cs.y;
        #pragma unroll
        for (int k = 0; k < 16; ++k) {
            ar[k] = cs.x*ar[k] + se*dpp_perm<0x4E>(ar[k]);
            ai[k] = cs.x*ai[k] + se*dpp_perm<0x4E>(ai[k]);
        }
    }
    {   // q7: xor1 (quad), sel sl0^sl2
        const float2 cs = *(const float2*)(lds + eb + 7*8 + 4);
        const float se = (sl0 ^ sl2) ? cs.y : -cs.y;
        #pragma unroll
        for (int k = 0; k < 16; ++k) {
            ar[k] = cs.x*ar[k] + se*dpp_perm<0xB1>(ar[k]);
            ai[k] = cs.x*ai[k] + se*dpp_perm<0xB1>(ai[k]);
        }
    }

    // ---- Z expectations: k-part Walsh (masks 0x7, 0xC, 0xE, 0xF) ----
    float P[16];
    #pragma unroll
    for (int k = 0; k < 16; ++k) P[k] = ar[k]*ar[k] + ai[k]*ai[k];

    float A_[8], D_[8];
    #pragma unroll
    for (int j = 0; j < 8; ++j) {
        A_[j] = P[2*j] + P[2*j+1];
        D_[j] = P[2*j] - P[2*j+1];
    }
    float DD[4], AD[4], AA[4];
    #pragma unroll
    for (int j = 0; j < 4; ++j) {
        DD[j] = D_[2*j] - D_[2*j+1];
        AD[j] = A_[2*j] - A_[2*j+1];
        AA[j] = A_[2*j] + A_[2*j+1];
    }
    const float G0  = DD[0] - DD[1], G1  = DD[2] - DD[3];
    const float GE0 = AD[0] - AD[1], GE1 = AD[2] - AD[3];
    const float GC0 = AA[0] - AA[1], GC1 = AA[2] - AA[3];
    float V7k = G0 + G1;     // mask 0x7 (K0K1K2)
    float VFk = G0 - G1;     // mask 0xF
    float VEk = GE0 - GE1;   // mask 0xE
    float VCk = GC0 - GC1;   // mask 0xC

    // ---- FWHT over 4 lane bits (ALL DPP; xor4 = xor7 o xor3) ----
    {
        const float g1 = (sl & 1) ? -1.f : 1.f;
        V7k = fmaf(g1, V7k, dpp_perm<0xB1>(V7k));
        VCk = fmaf(g1, VCk, dpp_perm<0xB1>(VCk));
        VEk = fmaf(g1, VEk, dpp_perm<0xB1>(VEk));
        VFk = fmaf(g1, VFk, dpp_perm<0xB1>(VFk));
        const float g2 = (sl & 2) ? -1.f : 1.f;
        V7k = fmaf(g2, V7k, dpp_perm<0x4E>(V7k));
        VCk = fmaf(g2, VCk, dpp_perm<0x4E>(VCk));
        VEk = fmaf(g2, VEk, dpp_perm<0x4E>(VEk));
        VFk = fmaf(g2, VFk, dpp_perm<0x4E>(VFk));
        const float g4 = (sl & 4) ? -1.f : 1.f;
        V7k = fmaf(g4, V7k, dpp_perm<0x1B>(dpp_perm<0x141>(V7k)));
        VCk = fmaf(g4, VCk, dpp_perm<0x1B>(dpp_perm<0x141>(VCk)));
        VEk = fmaf(g4, VEk, dpp_perm<0x1B>(dpp_perm<0x141>(VEk)));
        VFk = fmaf(g4, VFk, dpp_perm<0x1B>(dpp_perm<0x141>(VFk)));
        const float g8 = (sl & 8) ? -1.f : 1.f;
        V7k = fmaf(g8, V7k, dpp_perm<0x128>(V7k));
        VCk = fmaf(g8, VCk, dpp_perm<0x128>(VCk));
        VEk = fmaf(g8, VEk, dpp_perm<0x128>(VEk));
        VFk = fmaf(g8, VFk, dpp_perm<0x128>(VFk));
    }

    // ---- gather: q0:V7k@0xF q1:VCk@0 q2:VEk@0 q3:VFk@0 q4:VFk@8
    //              q5:VFk@0xC q6:VFk@0xA q7:VFk@0xF ----
    const float B7 = swz<0x1F0>(V7k);                // bcast lane15 of 16-grp
    const float BC = swz<0x010>(VCk);                // bcast lane0 of 16-grp
    const float BE = swz<0x010>(VEk);
    const int idx = (int)((0xFAC80000u >> ((sl & 7) * 4)) & 0xFu);
    const float BF = __shfl(VFk, (t & 0x30) | idx, 64);
    const float rsel = (sl == 0) ? B7 : (sl == 1) ? BC : (sl == 2) ? BE : BF;
    const float h = fast_tanh(rsel);
    if (sl < 8) {
        const size_t obase = (size_t)e * 8;
        out[obase + sl] = h;
        out[(size_t)B * 8 + obase + sl] = h;
    }
}

extern "C" void kernel_launch(void* const* d_in, const int* in_sizes, int n_in,
                              void* d_out, int out_size, void* d_ws, size_t ws_size,
                              hipStream_t stream)
{
    const float* inputs = (const float*)d_in[0];   // (B, 8) fp32
    const float* hidden = (const float*)d_in[1];   // (B, 2, 1, 8, 3) fp32
    float* out = (float*)d_out;                    // (2, B, 8) fp32 (tuple (h,h))
    const int B = in_sizes[0] / 8;                 // 16384
    const int blocks = (B + 15) / 16;              // 16 lanes per element
    hipLaunchKernelGGL(qcirc_kernel, dim3(blocks), dim3(256), 0, stream,
                       inputs, hidden, out, B);
}